// Round 3
// baseline (8996.816 us; speedup 1.0000x reference)
//
#include <hip/hip_runtime.h>
#include <hip/hip_bf16.h>

#define Bq 256
#define Nn 256
#define Dd 256
#define Uu 256

using bf16 = __hip_bfloat16;

__device__ __forceinline__ float b2f(bf16 v) { return __bfloat162float(v); }
__device__ __forceinline__ float sigf(float x) { return 1.0f / (1.0f + __expf(-x)); }
__device__ __forceinline__ float tanh_(float x) { return 2.0f / (1.0f + __expf(-2.0f * x)) - 1.0f; }

// 8 bf16 (uint4) dot 8 fp32 (two float4), accumulate into s
__device__ __forceinline__ void dot8(float& s, uint4 w, float4 h0, float4 h1) {
  s += __uint_as_float(w.x << 16)          * h0.x;
  s += __uint_as_float(w.x & 0xffff0000u)  * h0.y;
  s += __uint_as_float(w.y << 16)          * h0.z;
  s += __uint_as_float(w.y & 0xffff0000u)  * h0.w;
  s += __uint_as_float(w.z << 16)          * h1.x;
  s += __uint_as_float(w.z & 0xffff0000u)  * h1.y;
  s += __uint_as_float(w.w << 16)          * h1.z;
  s += __uint_as_float(w.w & 0xffff0000u)  * h1.w;
}

// ---- weight prep: cast fp32->bf16 AND permute so thread (j) reads its
// column as contiguous, wave-coalesced 16B chunks.
// wiouT2[(g*32 + c)*2048 + j*8 + e] = hiou[(c*8+e)*768 + g*256 + j]
// wfT2  [       c *2048 + j*8 + e] = hf  [(c*8+e)*256 + j]
__global__ __launch_bounds__(256) void prep_weights(
    const float* __restrict__ hiou, const float* __restrict__ hf,
    bf16* __restrict__ wiouT2, bf16* __restrict__ wfT2) {
  int idx = blockIdx.x * 256 + threadIdx.x;
  if (idx < 196608) {
    int e = idx & 7, j = (idx >> 3) & 255, c = (idx >> 11) & 31, g = idx >> 16;
    wiouT2[idx] = __float2bfloat16(hiou[(c * 8 + e) * 768 + g * 256 + j]);
  } else {
    int t = idx - 196608;
    int e = t & 7, j = (t >> 3) & 255, c = t >> 11;
    wfT2[t] = __float2bfloat16(hf[(c * 8 + e) * 256 + j]);
  }
}

// ---- phase 1: fiou_xb = inputs @ x_fiou + bias (unchanged from R2) ----
__global__ __launch_bounds__(256) void xproj(
    const float* __restrict__ x, const float* __restrict__ w,
    const float* __restrict__ bias, bf16* __restrict__ out) {
  __shared__ float xs[Dd][16];
  const int tid = threadIdx.x;
  const int row0 = blockIdx.x * 16;
  for (int i = 0; i < 16; ++i) {
    int idx = i * 256 + tid;
    int r = idx >> 8, k = idx & 255;
    xs[k][r] = x[(size_t)(row0 + r) * Dd + k];
  }
  __syncthreads();
  const int c0 = tid * 4;
  float4 bv = *(const float4*)(bias + c0);
  float acc[16][4];
#pragma unroll
  for (int r = 0; r < 16; ++r) {
    acc[r][0] = bv.x; acc[r][1] = bv.y; acc[r][2] = bv.z; acc[r][3] = bv.w;
  }
  for (int k = 0; k < Dd; ++k) {
    float4 wv = *(const float4*)(w + (size_t)k * 1024 + c0);
    const float4* xr = (const float4*)xs[k];
    float4 x0 = xr[0], x1 = xr[1], x2 = xr[2], x3 = xr[3];
    float xv[16] = {x0.x, x0.y, x0.z, x0.w, x1.x, x1.y, x1.z, x1.w,
                    x2.x, x2.y, x2.z, x2.w, x3.x, x3.y, x3.z, x3.w};
#pragma unroll
    for (int r = 0; r < 16; ++r) {
      acc[r][0] += xv[r] * wv.x;
      acc[r][1] += xv[r] * wv.y;
      acc[r][2] += xv[r] * wv.z;
      acc[r][3] += xv[r] * wv.w;
    }
  }
#pragma unroll
  for (int r = 0; r < 16; ++r) {
    union { ushort4 u4; bf16 b[4]; } pk;
    pk.b[0] = __float2bfloat16(acc[r][0]);
    pk.b[1] = __float2bfloat16(acc[r][1]);
    pk.b[2] = __float2bfloat16(acc[r][2]);
    pk.b[3] = __float2bfloat16(acc[r][3]);
    *(ushort4*)(&out[(size_t)(row0 + r) * 1024 + c0]) = pk.u4;
  }
}

// ---- phase 2: scan v2. Block = 1024 threads (16 waves), one batch/block.
// j = tid&255 (output unit), q = tid>>8 (k-quarter, 64 k's each).
// LDS: wf (128KB, resident) | par partials 12KB | hvec 1KB | ovec 1KB | node 4KB
#define LDS_BYTES (131072 + 12288 + 1024 + 1024 + 4096)
extern __shared__ char smem[];

__global__ __launch_bounds__(1024, 4) void scan2(
    const bf16* __restrict__ fiou, const int* __restrict__ parents,
    const int* __restrict__ post, const bf16* __restrict__ wiouT2,
    const bf16* __restrict__ wfT2, float* __restrict__ X,
    float* __restrict__ gcs) {
  bf16*  wf_l  = (bf16*)smem;
  float* par_l = (float*)(smem + 131072);          // [3][4][256]
  float* hvec  = (float*)(smem + 131072 + 12288);  // [256]
  float* ovec  = hvec + 256;                       // [256]
  int4*  node  = (int4*)(smem + 131072 + 12288 + 2048);  // [256]

  const int tid = threadIdx.x;
  const int j = tid & 255;
  const int q = tid >> 8;
  const int b = blockIdx.x;
  const int base = b * Nn;

  // stage wf into LDS (coalesced 16B)
  {
    const uint4* src = (const uint4*)wfT2;
    uint4* dst = (uint4*)wf_l;
    for (int i = tid; i < 65536 / 8; i += 1024) dst[i] = src[i];
  }
  // precompute node info (tgt, par, om, pm) per step
  if (tid < Nn) {
    int po = post[base + tid];
    int om = po >= 0;
    int tgt = om ? po : 0;
    int praw = parents[base + tgt];
    int pm = (praw >= 0) && om;
    int par = praw >= 0 ? praw : 0;
    node[tid] = make_int4(tgt, par, om, pm);
  }
  __syncthreads();

  const uint4* wiou4 = (const uint4*)wiouT2;  // idx (g*32+c)*256 + j
  const uint4* wf4   = (const uint4*)wf_l;    // idx c*256 + j

  int4 nd = node[0];
  bool fwd = false;
  float fwd_h = 0.f, fwd_g = 0.f;

  for (int t = 0; t < Nn; ++t) {
    int4 ndn = node[t < Nn - 1 ? t + 1 : t];  // prefetch next step's node info
    const int tgt = nd.x, par = nd.y, om = nd.z, pm = nd.w;
    const size_t tb = (size_t)(base + tgt) * 256;
    const size_t pb = (size_t)(base + par) * 256;
    const size_t fb = (size_t)(base + tgt) * 1024;

    float gc = 0.f, xi = 0.f, xo = 0.f, xu = 0.f, xf = 0.f, xold = 0.f, gold = 0.f;
    if (q == 0) {
      float hv;
      if (fwd) { hv = fwd_h; gc = fwd_g; }
      else     { hv = X[tb + j]; gc = gcs[tb + j]; }
      hvec[j] = hv;
      // prefetch everything needed after B2/B4 (latency hidden by iou phase)
      xi = b2f(fiou[fb + 256 + j]);
      xo = b2f(fiou[fb + 512 + j]);
      xu = b2f(fiou[fb + 768 + j]);
      xf = b2f(fiou[(size_t)(base + par) * 1024 + j]);
      xold = X[pb + j];
      gold = gcs[pb + j];
    }
    __syncthreads();  // B1: hvec ready

    // iou partials over k in [64q, 64q+64)
    float ai = 0.f, ao = 0.f, au = 0.f;
    {
      const float4* hv4 = (const float4*)(hvec + q * 64);
#pragma unroll
      for (int cc = 0; cc < 8; ++cc) {
        int c = q * 8 + cc;
        float4 h0 = hv4[cc * 2];
        float4 h1 = hv4[cc * 2 + 1];
        uint4 wi = wiou4[(0 * 32 + c) * 256 + j];
        uint4 wo = wiou4[(1 * 32 + c) * 256 + j];
        uint4 wu = wiou4[(2 * 32 + c) * 256 + j];
        dot8(ai, wi, h0, h1);
        dot8(ao, wo, h0, h1);
        dot8(au, wu, h0, h1);
      }
    }
    par_l[(0 * 4 + q) * 256 + j] = ai;
    par_l[(1 * 4 + q) * 256 + j] = ao;
    par_l[(2 * 4 + q) * 256 + j] = au;
    __syncthreads();  // B2: iou partials ready

    float mem = 0.f, out = 0.f;
    if (q == 0) {
      float I = xi + par_l[j] + par_l[256 + j] + par_l[512 + j] + par_l[768 + j];
      float O = xo + par_l[1024 + j] + par_l[1280 + j] + par_l[1536 + j] + par_l[1792 + j];
      float U = xu + par_l[2048 + j] + par_l[2304 + j] + par_l[2560 + j] + par_l[2816 + j];
      mem = sigf(I) * tanh_(U) + gc;
      out = sigf(O) * tanh_(mem);
      ovec[j] = out;
    }
    __syncthreads();  // B3: ovec ready, par_l reusable

    // f partials (weights from LDS)
    float af = 0.f;
    {
      const float4* ov4 = (const float4*)(ovec + q * 64);
#pragma unroll
      for (int cc = 0; cc < 8; ++cc) {
        int c = q * 8 + cc;
        float4 o0 = ov4[cc * 2];
        float4 o1 = ov4[cc * 2 + 1];
        uint4 wv = wf4[c * 256 + j];
        dot8(af, wv, o0, o1);
      }
    }
    par_l[q * 256 + j] = af;
    __syncthreads();  // B4: f partials ready

    if (q == 0) {
      float AF = xf + par_l[j] + par_l[256 + j] + par_l[512 + j] + par_l[768 + j];
      float gated = sigf(AF) * mem;
      if (om) X[tb + j] = out;  // hs[tgt] (overwrites consumed csh)
      if (pm) {
        float xnew = xold + out;
        float gnew = gold + gated;
        X[pb + j] = xnew;    // csh[par] += out
        gcs[pb + j] = gnew;  // gcs[par] += gated
        // chain forwarding: if next step consumes exactly this node, skip the
        // global round-trip (only thread (j,0) ever writes column j of batch b)
        fwd = (par == ndn.x);
        fwd_h = xnew;
        fwd_g = gnew;
      } else {
        fwd = false;
      }
    }
    nd = ndn;
  }
}

extern "C" void kernel_launch(void* const* d_in, const int* in_sizes, int n_in,
                              void* d_out, int out_size, void* d_ws, size_t ws_size,
                              hipStream_t stream) {
  const float* inputs = (const float*)d_in[0];
  const int* parents  = (const int*)d_in[1];
  const int* post     = (const int*)d_in[2];
  const float* xw     = (const float*)d_in[3];
  const float* hf     = (const float*)d_in[4];
  const float* hiou   = (const float*)d_in[5];
  const float* bias   = (const float*)d_in[6];
  float* X = (float*)d_out;  // csh-then-hs buffer

  // ws layout (~192.7 MiB):
  //   [0, 128 MiB)        fiou_xb bf16 (B*N*4U)
  //   [128, 192 MiB)      gcs fp32     (B*N*U)
  //   [192 MiB, +384 KiB) wiouT2 bf16
  //   then +128 KiB       wfT2 bf16
  char* ws = (char*)d_ws;
  bf16* fiou    = (bf16*)ws;
  float* gcs    = (float*)(ws + (size_t)134217728);
  bf16* wiouT2  = (bf16*)(ws + (size_t)201326592);
  bf16* wfT2    = (bf16*)(ws + (size_t)201326592 + 393216);

  hipMemsetAsync(X, 0, (size_t)Bq * Nn * Uu * sizeof(float), stream);
  hipMemsetAsync(gcs, 0, (size_t)Bq * Nn * Uu * sizeof(float), stream);

  hipFuncSetAttribute(reinterpret_cast<const void*>(scan2),
                      hipFuncAttributeMaxDynamicSharedMemorySize, LDS_BYTES);

  prep_weights<<<1024, 256, 0, stream>>>(hiou, hf, wiouT2, wfT2);
  xproj<<<(Bq * Nn) / 16, 256, 0, stream>>>(inputs, xw, bias, fiou);
  scan2<<<Bq, 1024, LDS_BYTES, stream>>>(fiou, parents, post, wiouT2, wfT2, X, gcs);
}

// Round 4
// 3278.072 us; speedup vs baseline: 2.7445x; 2.7445x over previous
//
#include <hip/hip_runtime.h>
#include <hip/hip_bf16.h>

#define Bq 256
#define Nn 256
#define Dd 256
#define Uu 256

using bf16 = __hip_bfloat16;

typedef __attribute__((ext_vector_type(8))) short s16x8;
typedef __attribute__((ext_vector_type(4))) float f32x4;

__device__ __forceinline__ float bu2f(unsigned short u) {
  return __uint_as_float(((unsigned)u) << 16);
}
__device__ __forceinline__ unsigned short f2bu(float f) {
  union { bf16 h; unsigned short u; } c; c.h = __float2bfloat16(f); return c.u;
}
__device__ __forceinline__ float sigf(float x) { return 1.0f / (1.0f + __expf(-x)); }
__device__ __forceinline__ float tanh_(float x) { return 2.0f / (1.0f + __expf(-2.0f * x)) - 1.0f; }
__device__ __forceinline__ s16x8 asv(uint4 x) {
  union { uint4 u; s16x8 v; } c; c.u = x; return c.v;
}
#define MFMA16(a, b, c) __builtin_amdgcn_mfma_f32_16x16x32_bf16(a, b, c, 0, 0, 0)

// ---- weight prep: build MFMA B-fragments (bf16) for wiou and wf ----
// wiouB frag (g,nt,kt), lane l, elem e:  = hiou[(kt*32+(l>>4)*8+e)*768 + g*256+nt*16+(l&15)]
// wfB   frag (nt,kt):                    = hf  [(kt*32+(l>>4)*8+e)*256 +        nt*16+(l&15)]
__global__ __launch_bounds__(256) void prep_weights(
    const float* __restrict__ hiou, const float* __restrict__ hf,
    bf16* __restrict__ wiouB, bf16* __restrict__ wfB) {
  int idx = blockIdx.x * 256 + threadIdx.x;  // 262144 total
  int e = idx & 7, l = (idx >> 3) & 63, kt = (idx >> 9) & 7;
  int k = kt * 32 + (l >> 4) * 8 + e;
  if (idx < 196608) {
    int nt = (idx >> 12) & 15, g = idx >> 16;
    wiouB[idx] = __float2bfloat16(hiou[k * 768 + g * 256 + nt * 16 + (l & 15)]);
  } else {
    int t = idx - 196608;
    int nt = (t >> 12) & 15;
    wfB[t] = __float2bfloat16(hf[k * 256 + nt * 16 + (l & 15)]);
  }
}

// ---- node-info table: nd[blk][t][m] = tgt | par<<8 | om<<16 | pm<<17 ----
__global__ __launch_bounds__(256) void prep_nd(
    const int* __restrict__ parents, const int* __restrict__ post,
    unsigned* __restrict__ ndg) {
  int idx = blockIdx.x * 256 + threadIdx.x;  // 65536
  int b = idx >> 8, t = idx & 255;
  int po = post[b * 256 + t];
  int om = po >= 0;
  int tgt = om ? po : 0;
  int praw = parents[b * 256 + tgt];
  int pm = (praw >= 0) && om;
  int par = praw >= 0 ? praw : 0;
  unsigned word = (unsigned)(tgt & 255) | ((unsigned)(par & 255) << 8) |
                  ((unsigned)om << 16) | ((unsigned)pm << 17);
  ndg[(b >> 4) * 4096 + t * 16 + (b & 15)] = word;
}

// ---- phase 1: fiou_xb = inputs @ x_fiou + bias (VALU, unchanged) ----
__global__ __launch_bounds__(256) void xproj(
    const float* __restrict__ x, const float* __restrict__ w,
    const float* __restrict__ bias, bf16* __restrict__ out) {
  __shared__ float xs[Dd][16];
  const int tid = threadIdx.x;
  const int row0 = blockIdx.x * 16;
  for (int i = 0; i < 16; ++i) {
    int idx = i * 256 + tid;
    int r = idx >> 8, k = idx & 255;
    xs[k][r] = x[(size_t)(row0 + r) * Dd + k];
  }
  __syncthreads();
  const int c0 = tid * 4;
  float4 bv = *(const float4*)(bias + c0);
  float acc[16][4];
#pragma unroll
  for (int r = 0; r < 16; ++r) {
    acc[r][0] = bv.x; acc[r][1] = bv.y; acc[r][2] = bv.z; acc[r][3] = bv.w;
  }
  for (int k = 0; k < Dd; ++k) {
    float4 wv = *(const float4*)(w + (size_t)k * 1024 + c0);
    const float4* xr = (const float4*)xs[k];
    float4 x0 = xr[0], x1 = xr[1], x2 = xr[2], x3 = xr[3];
    float xv[16] = {x0.x, x0.y, x0.z, x0.w, x1.x, x1.y, x1.z, x1.w,
                    x2.x, x2.y, x2.z, x2.w, x3.x, x3.y, x3.z, x3.w};
#pragma unroll
    for (int r = 0; r < 16; ++r) {
      acc[r][0] += xv[r] * wv.x;
      acc[r][1] += xv[r] * wv.y;
      acc[r][2] += xv[r] * wv.z;
      acc[r][3] += xv[r] * wv.w;
    }
  }
#pragma unroll
  for (int r = 0; r < 16; ++r) {
    union { ushort4 u4; bf16 b[4]; } pk;
    pk.b[0] = __float2bfloat16(acc[r][0]);
    pk.b[1] = __float2bfloat16(acc[r][1]);
    pk.b[2] = __float2bfloat16(acc[r][2]);
    pk.b[3] = __float2bfloat16(acc[r][3]);
    *(ushort4*)(&out[(size_t)(row0 + r) * 1024 + c0]) = pk.u4;
  }
}

// ---- phase 2: weight-stationary MFMA scan ----
// 16 blocks x 512 threads (8 waves). Block owns 16 batches (M=16).
// Wave w owns output cols j in [32w, 32w+32) for gates i,o,u and f.
// wiou B-frags in VGPRs (48 x uint4), wf B-frags in LDS (128 KB).
#define LDH 264
#define SCAN_LDS (131072 + 2 * 16 * LDH * 2)
extern __shared__ char smem[];

__global__ __launch_bounds__(512, 1) void scan3(
    const unsigned short* __restrict__ fiou, const unsigned short* __restrict__ wiouB,
    const unsigned short* __restrict__ wfB, const unsigned* __restrict__ ndg,
    float* __restrict__ X, float* __restrict__ gcs) {
  unsigned short* wf_l  = (unsigned short*)smem;            // 65536 elems
  unsigned short* h_lds = (unsigned short*)(smem + 131072); // 16 x LDH
  unsigned short* o_lds = h_lds + 16 * LDH;                 // 16 x LDH

  const int tid = threadIdx.x;
  const int w = tid >> 6, l = tid & 63;
  const int lm = l & 15, lq = l >> 4;
  const int blk = blockIdx.x;
  const int jj = 32 * w + lm;

  // load wiou B-fragments into registers
  uint4 wB[3][2][8];
  {
    const uint4* s = (const uint4*)wiouB;
#pragma unroll
    for (int g = 0; g < 3; ++g)
#pragma unroll
      for (int ts = 0; ts < 2; ++ts)
#pragma unroll
        for (int kt = 0; kt < 8; ++kt)
          wB[g][ts][kt] = s[((g * 16 + (2 * w + ts)) * 8 + kt) * 64 + l];
  }
  // stage wf B-fragments into LDS
  {
    const uint4* s = (const uint4*)wfB;
    uint4* d = (uint4*)wf_l;
    for (int i = tid; i < 8192; i += 512) d[i] = s[i];
  }
  const unsigned* ndb = ndg + blk * 4096;
  const uint4* ndb4 = (const uint4*)ndb;
  uint4 cur4 = ndb4[lq];
  unsigned cur_g = ndb[tid >> 5];
  __syncthreads();

  for (int t = 0; t < Nn; ++t) {
    // A) h-gather: 16 rows of csh (X) -> bf16 -> h_lds
    {
      const int r16 = tid >> 5, c8 = (tid & 31) * 8;
      int nr = ((blk * 16 + r16) << 8) + (int)(cur_g & 255);
      const float* xr = X + ((size_t)nr << 8) + c8;
      float4 a0 = ((const float4*)xr)[0];
      float4 a1 = ((const float4*)xr)[1];
      ushort4 p0, p1;
      p0.x = f2bu(a0.x); p0.y = f2bu(a0.y); p0.z = f2bu(a0.z); p0.w = f2bu(a0.w);
      p1.x = f2bu(a1.x); p1.y = f2bu(a1.y); p1.z = f2bu(a1.z); p1.w = f2bu(a1.w);
      *(ushort4*)&h_lds[r16 * LDH + c8] = p0;
      *(ushort4*)&h_lds[r16 * LDH + c8 + 4] = p1;
    }
    __syncthreads();  // B1: h_lds ready

    // prefetch next step's node info
    const int tn = t < Nn - 1 ? t + 1 : t;
    uint4 nxt4 = ndb4[tn * 4 + lq];
    unsigned nxt_g = ndb[tn * 16 + (tid >> 5)];

    unsigned ndr[4] = {cur4.x, cur4.y, cur4.z, cur4.w};

    // C) issue raw gating loads (consumed after MFMA)
    unsigned short rxi[2][4], rxo[2][4], rxu[2][4], rxf[2][4];
    float rgc[2][4];
#pragma unroll
    for (int r = 0; r < 4; ++r) {
      int tgt = ndr[r] & 255, par = (ndr[r] >> 8) & 255;
      int nb = (blk * 16 + 4 * lq + r) << 8;
      int nrT = nb + tgt, nrP = nb + par;
      const unsigned short* fT = fiou + ((size_t)nrT << 10);
      const unsigned short* fP = fiou + ((size_t)nrP << 10);
#pragma unroll
      for (int ts = 0; ts < 2; ++ts) {
        int j = jj + ts * 16;
        rxi[ts][r] = fT[256 + j];
        rxo[ts][r] = fT[512 + j];
        rxu[ts][r] = fT[768 + j];
        rxf[ts][r] = fP[j];
        rgc[ts][r] = gcs[((size_t)nrT << 8) + j];
      }
    }

    // D) iou MFMA: h(16x256) @ wiou(256x768), per-wave 2 col-tiles x 3 gates
    f32x4 z4 = {0.f, 0.f, 0.f, 0.f};
    f32x4 aI[2] = {z4, z4}, aO[2] = {z4, z4}, aU[2] = {z4, z4};
#pragma unroll
    for (int kt = 0; kt < 8; ++kt) {
      uint4 av = *(const uint4*)&h_lds[lm * LDH + kt * 32 + lq * 8];
      s16x8 a = asv(av);
#pragma unroll
      for (int ts = 0; ts < 2; ++ts) {
        aI[ts] = MFMA16(a, asv(wB[0][ts][kt]), aI[ts]);
        aO[ts] = MFMA16(a, asv(wB[1][ts][kt]), aO[ts]);
        aU[ts] = MFMA16(a, asv(wB[2][ts][kt]), aU[ts]);
      }
    }

    // E) gating (registers; lane owns (m = 4*lq+r, j = jj+16*ts))
    float mem_[2][4], out_[2][4], xold[2][4], gold[2][4];
#pragma unroll
    for (int ts = 0; ts < 2; ++ts)
#pragma unroll
      for (int r = 0; r < 4; ++r) {
        float I = aI[ts][r] + bu2f(rxi[ts][r]);
        float O = aO[ts][r] + bu2f(rxo[ts][r]);
        float Uv = aU[ts][r] + bu2f(rxu[ts][r]);
        float memv = sigf(I) * tanh_(Uv) + rgc[ts][r];
        float outv = sigf(O) * tanh_(memv);
        mem_[ts][r] = memv;
        out_[ts][r] = outv;
        o_lds[(4 * lq + r) * LDH + jj + ts * 16] = f2bu(outv);
      }
    // issue parent RMW loads (consumed in epilogue)
#pragma unroll
    for (int r = 0; r < 4; ++r) {
      int par = (ndr[r] >> 8) & 255;
      int nrP = ((blk * 16 + 4 * lq + r) << 8) + par;
#pragma unroll
      for (int ts = 0; ts < 2; ++ts) {
        xold[ts][r] = X[((size_t)nrP << 8) + jj + ts * 16];
        gold[ts][r] = gcs[((size_t)nrP << 8) + jj + ts * 16];
      }
    }
    __syncthreads();  // B2: o_lds ready

    // G) f MFMA: out(16x256) @ wf(256x256), wf frags from LDS
    f32x4 aF[2] = {z4, z4};
#pragma unroll
    for (int kt = 0; kt < 8; ++kt) {
      uint4 av = *(const uint4*)&o_lds[lm * LDH + kt * 32 + lq * 8];
      s16x8 a = asv(av);
#pragma unroll
      for (int ts = 0; ts < 2; ++ts) {
        uint4 bv = *(const uint4*)&wf_l[(((2 * w + ts) * 8 + kt) * 64 + l) * 8];
        aF[ts] = MFMA16(a, asv(bv), aF[ts]);
      }
    }

    // H) epilogue: hs write + parent csh/gcs accumulate
#pragma unroll
    for (int ts = 0; ts < 2; ++ts)
#pragma unroll
      for (int r = 0; r < 4; ++r) {
        unsigned nd_ = ndr[r];
        int tgt = nd_ & 255, par = (nd_ >> 8) & 255;
        int nb = (blk * 16 + 4 * lq + r) << 8;
        int j = jj + ts * 16;
        float AF = aF[ts][r] + bu2f(rxf[ts][r]);
        float gated = sigf(AF) * mem_[ts][r];
        if (nd_ & 0x10000u) X[((size_t)(nb + tgt) << 8) + j] = out_[ts][r];
        if (nd_ & 0x20000u) {
          X[((size_t)(nb + par) << 8) + j] = xold[ts][r] + out_[ts][r];
          gcs[((size_t)(nb + par) << 8) + j] = gold[ts][r] + gated;
        }
      }
    __syncthreads();  // B3: epilogue visible before next h-gather
    cur4 = nxt4;
    cur_g = nxt_g;
  }
}

extern "C" void kernel_launch(void* const* d_in, const int* in_sizes, int n_in,
                              void* d_out, int out_size, void* d_ws, size_t ws_size,
                              hipStream_t stream) {
  const float* inputs = (const float*)d_in[0];
  const int* parents  = (const int*)d_in[1];
  const int* post     = (const int*)d_in[2];
  const float* xw     = (const float*)d_in[3];
  const float* hf     = (const float*)d_in[4];
  const float* hiou   = (const float*)d_in[5];
  const float* bias   = (const float*)d_in[6];
  float* X = (float*)d_out;  // csh-then-hs buffer

  // ws layout (~192.8 MiB):
  //   [0, 128 MiB)   fiou_xb bf16  (B*N*4U)
  //   +134217728     gcs fp32      (B*N*U)   64 MiB
  //   +201326592     wiouB bf16    384 KiB
  //   +201719808     wfB bf16      128 KiB
  //   +201850880     ndg u32       256 KiB
  char* ws = (char*)d_ws;
  bf16* fiou     = (bf16*)ws;
  float* gcs     = (float*)(ws + (size_t)134217728);
  bf16* wiouB    = (bf16*)(ws + (size_t)201326592);
  bf16* wfB      = (bf16*)(ws + (size_t)201719808);
  unsigned* ndg  = (unsigned*)(ws + (size_t)201850880);

  hipMemsetAsync(X, 0, (size_t)Bq * Nn * Uu * sizeof(float), stream);
  hipMemsetAsync(gcs, 0, (size_t)Bq * Nn * Uu * sizeof(float), stream);

  hipFuncSetAttribute(reinterpret_cast<const void*>(scan3),
                      hipFuncAttributeMaxDynamicSharedMemorySize, SCAN_LDS);

  prep_weights<<<1024, 256, 0, stream>>>(hiou, hf, wiouB, wfB);
  prep_nd<<<256, 256, 0, stream>>>(parents, post, ndg);
  xproj<<<(Bq * Nn) / 16, 256, 0, stream>>>(inputs, xw, bias, (bf16*)fiou);
  scan3<<<16, 512, SCAN_LDS, stream>>>((const unsigned short*)fiou,
                                       (const unsigned short*)wiouB,
                                       (const unsigned short*)wfB,
                                       ndg, X, gcs);
}